// Round 9
// baseline (192.250 us; speedup 1.0000x reference)
//
#include <hip/hip_runtime.h>
#include <hip/hip_bf16.h>

// ProbableConv2d: selection-first implementation.
// B=8, CI=128, CO=256, H=W=56, P=9, K=3.
//
// 4 dispatches:
//   memset cnt (64 B)
//   k_front : fused, 512-thr blocks —
//             [0..391]    obs: fp32 observer -> argmax -> per-path lists.
//                         R9: barrier-free per-thread coalesced x loads with
//                         depth-2 rotating prefetch (R8's per-chunk
//                         global_load_lds+syncthreads exposed full load
//                         latency at every chunk: 11% duty cycle, 48us).
//             [392..839]  xpose: x -> x_pad NHWC bf16 via padded LDS tile.
//             [840..1415] wprep: kw -> W2 bf16 via LDS transpose, 4 pco/block.
//   k_conv  : per (path, co-half, 64-px tile) gathered-GEMM, MFMA bf16.
//             R9: epilogue writes pixel-indexed outp[pix][co] bf16 directly
//             (512 B/row fully written -> no partial-line amplification);
//             pix2row indirection dropped.
//   k_out   : pure streaming: contiguous outp reads -> LDS (padded rows) ->
//             coalesced NCHW f32 stores. No gather.

typedef unsigned int u32;

#define NPIX    25088      // 8*56*56
#define OFF_LIST 4096
#define OFF_XPAD 907264                      // 4096 + 9*25088*4
#define OFF_W2   7796736                     // + 8*58*58*128*2
#define OFF_OUTP 13105152                    // + 1327104*4  (outp: 25088*256*2 B)

__device__ __forceinline__ unsigned short f2bf(float f) {
  u32 u = __builtin_bit_cast(u32, f);
  u32 r = (u + 0x7FFFu + ((u >> 16) & 1u)) >> 16;
  return (unsigned short)r;
}
__device__ __forceinline__ float bflo(u32 w) {
  return __builtin_bit_cast(float, w << 16);
}
__device__ __forceinline__ float bfhi(u32 w) {
  return __builtin_bit_cast(float, w & 0xFFFF0000u);
}

#define GLDS16(g, l)                                                        \
  __builtin_amdgcn_global_load_lds(                                         \
      (const __attribute__((address_space(1))) u32*)(g),                    \
      (__attribute__((address_space(3))) u32*)(l), 16, 0, 0)

typedef __attribute__((ext_vector_type(8))) short bf16x8;
typedef __attribute__((ext_vector_type(4))) float f32x4;

// ---------------------------------------------------------------- fused front-end
__global__ __launch_bounds__(512) void k_front(
    const float* __restrict__ x, const float* __restrict__ kw,
    const float* __restrict__ ow1, const float* __restrict__ ob1,
    const float* __restrict__ ow2, const float* __restrict__ ob2,
    u32* __restrict__ xpad, u32* __restrict__ w2,
    int* __restrict__ cnt, int* __restrict__ list) {
  // overlays: obs red[8][64][9] f32 / xpose xt[56*65] u32 / wprep kt[4608] f32
  __shared__ __attribute__((aligned(16))) char smraw[18432];
  __shared__ int lcnt[9], lbase[9];

  int bid = blockIdx.x;
  int tid = threadIdx.x;
  int ln = tid & 63, wv = tid >> 6;

  if (bid < 392) {
    // ---------------- observer + argmax + compaction (64 px x 8 d-groups)
    float* red = (float*)smraw;          // [8][64][9]
    int dgu = __builtin_amdgcn_readfirstlane(wv);   // provably wave-uniform
    int pix = bid * 64 + ln;        // block stays in one b (3136 % 64 == 0)
    int b = pix / 3136, s = pix - b * 3136;
    const float* xb = x + (size_t)b * 401408 + s;   // lanes consecutive

    if (tid < 9) lcnt[tid] = 0;

    float h[16];
    const float* o1 = ob1 + dgu * 16;               // scalar loads
#pragma unroll
    for (int i = 0; i < 16; ++i) h[i] = o1[i];
    const float* w1b = ow1 + dgu * 16 * 128;        // uniform base

    // depth-2 prefetch, 3 rotating buffers; full unroll -> SSA, no movs
    float bufs[3][8];
#pragma unroll
    for (int j = 0; j < 8; ++j) bufs[0][j] = xb[(size_t)j * 3136];
#pragma unroll
    for (int j = 0; j < 8; ++j) bufs[1][j] = xb[(size_t)(8 + j) * 3136];

#pragma unroll
    for (int c = 0; c < 16; ++c) {
      if (c + 2 < 16) {
        const int bi = (c + 2) % 3;
#pragma unroll
        for (int j = 0; j < 8; ++j)
          bufs[bi][j] = xb[(size_t)((c + 2) * 8 + j) * 3136];
      }
      const int cur = c % 3;
#pragma unroll
      for (int i = 0; i < 16; ++i) {
        const float* wr = w1b + i * 128 + c * 8;    // uniform -> s_load
        float a = h[i];
#pragma unroll
        for (int j = 0; j < 8; ++j) a = fmaf(wr[j], bufs[cur][j], a);
        h[i] = a;
      }
    }

#pragma unroll
    for (int i = 0; i < 16; ++i) h[i] = tanhf(h[i]);

#pragma unroll
    for (int p = 0; p < 9; ++p) {
      float sc = 0.f;
      const float* wr = ow2 + p * 128 + dgu * 16;   // scalar loads
#pragma unroll
      for (int i = 0; i < 16; ++i) sc = fmaf(wr[i], h[i], sc);
      red[wv * 576 + ln * 9 + p] = sc;    // stride-9 -> 2-way alias (free)
    }
    __syncthreads();

    int bi = 0, slot = 0;
    if (wv == 0) {
      float best = 0.f;
#pragma unroll
      for (int p = 0; p < 9; ++p) {
        float v = ob2[p];
#pragma unroll
        for (int g = 0; g < 8; ++g) v += red[g * 576 + ln * 9 + p];  // asc-d
        if (p == 0 || v > best) { best = v; bi = p; }  // strict >: np argmax
      }
      slot = atomicAdd(&lcnt[bi], 1);     // LDS atomic
    }
    __syncthreads();
    if (tid < 9) lbase[tid] = atomicAdd(&cnt[tid], lcnt[tid]);
    __syncthreads();
    if (wv == 0) list[bi * NPIX + lbase[bi] + slot] = pix;

  } else if (bid < 840) {
    // ---------------- x (NCHW f32) -> x_pad row (b,h+1), fully coalesced
    u32* xt = (u32*)smraw;               // [56][65] padded
    int bh = bid - 392;                  // 0..447 = b*56+h
    int b = bh / 56, hh = bh - b * 56;
    const float* xr = x + (size_t)b * 401408 + hh * 56;
#pragma unroll
    for (int r = 0; r < 8; ++r) {
      int ci = wv * 16 + 2 * r;
      if (ln < 56) {
        float f0 = xr[(size_t)ci * 3136 + ln];
        float f1 = xr[(size_t)(ci + 1) * 3136 + ln];
        xt[ln * 65 + (ci >> 1)] = (u32)f2bf(f0) | ((u32)f2bf(f1) << 16);
      }
    }
    __syncthreads();
    u32* orow = xpad + (size_t)(b * 58 + hh + 1) * 58 * 64;
    for (int w = wv; w < 56; w += 8)
      orow[(w + 1) * 64 + ln] = xt[w * 65 + ln];
    if (wv == 0) orow[ln] = 0;                // halo col 0
    else if (wv == 1) orow[57 * 64 + ln] = 0; // halo col 57
    if (hh == 0) {
      u32* hrow = xpad + (size_t)(b * 58) * 58 * 64;
      for (int i = tid; i < 58 * 64; i += 512) hrow[i] = 0;
    } else if (hh == 55) {
      u32* hrow = xpad + (size_t)(b * 58 + 57) * 58 * 64;
      for (int i = tid; i < 58 * 64; i += 512) hrow[i] = 0;
    }

  } else {
    // ---------------- kw (P,CO,CI,3,3) f32 -> W2 (P,CO,1152) bf16, 4 pco/block
    float* kt = (float*)smraw;           // [4*1152]
    int base = (bid - 840) * 4;          // pco quad
    const float* src = kw + (size_t)base * 1152;
#pragma unroll
    for (int i = 0; i < 9; ++i) kt[i * 512 + tid] = src[i * 512 + tid];
    __syncthreads();
    for (int t = tid; t < 2304; t += 512) {
      int pl = t / 576, d = t - pl * 576;
      int tap = d >> 6, cp = d & 63;
      float v0 = kt[pl * 1152 + 18 * cp + tap];
      float v1 = kt[pl * 1152 + 18 * cp + 9 + tap];
      w2[(size_t)(base + pl) * 576 + d] = (u32)f2bf(v0) | ((u32)f2bf(v1) << 16);
    }
  }
}

// ---------------------------------------------------------------- gathered GEMM conv
__global__ __launch_bounds__(256, 4) void k_conv(
    const int* __restrict__ cnt, const int* __restrict__ list,
    const char* __restrict__ xpadB, const char* __restrict__ w2B,
    const float* __restrict__ kb, unsigned short* __restrict__ outp) {
  __shared__ short Wlds[2][4096];  // [buf][co(128) x k(32)], k-seg XOR-swizzled
  __shared__ short Plds[2][2048];  // [buf][px(64) x k(32)],  k-seg XOR-swizzled
  __shared__ int offsB[64], pixSB[64];
  __shared__ float kbl[128];

  int bid = blockIdx.x;
  int half = bid & 1, tb = bid >> 1;
  int p = -1, cntp = 0;
  for (int pp = 0; pp < 9; ++pp) {     // uniform scan: block -> (path, tile)
    int c = cnt[pp];
    int tt = (c + 63) >> 6;
    if (p < 0) {
      if (tb < tt) { p = pp; cntp = c; }
      else tb -= tt;
    }
  }
  if (p < 0) return;
  int nbase = tb * 64;
  int tid = threadIdx.x;

  if (tid < 64) {
    int g = nbase + tid;
    int pixid = list[p * NPIX + (g < cntp ? g : nbase)];
    int b = pixid / 3136, s = pixid - b * 3136;
    int h = s / 56, w = s - h * 56;
    offsB[tid] = ((b * 58 + h) * 58 + w) * 256;  // byte offset of tap(0,0)
    pixSB[tid] = pixid;
  }
  if (tid < 128) kbl[tid] = kb[p * 256 + half * 128 + tid];
  __syncthreads();

  // stage: LDS slot s of row r holds global k-segment s ^ ((r>>1)&3)
  int segsw = ((tid & 3) ^ ((tid >> 3) & 3)) * 16;   // byte offset of segment
  int na = tid >> 2;                                 // row 0..63
  int offP = offsB[na] + segsw;
  const char* wrow = w2B + (size_t)(p * 256 + half * 128) * 2304;
  const char* wp0 = wrow + (size_t)na * 2304 + segsw;
  const char* wp1 = wrow + (size_t)(64 + na) * 2304 + segsw;

  auto stage = [&](int c, int q) {
    int tap = c >> 2, kc = c & 3;
    int wko = tap * 256 + kc * 64;                          // bytes in W row
    int tapoff = ((tap / 3) * 58 + (tap % 3)) * 256 + kc * 64;  // bytes in x_pad
    GLDS16(wp0 + wko, &Wlds[q][tid * 8]);
    GLDS16(wp1 + wko, &Wlds[q][2048 + tid * 8]);
    GLDS16(xpadB + (size_t)(offP + tapoff), &Plds[q][tid * 8]);
  };

  f32x4 acc[4][2];
#pragma unroll
  for (int mt = 0; mt < 4; ++mt)
#pragma unroll
    for (int nt = 0; nt < 2; ++nt) acc[mt][nt] = (f32x4)0.f;

  int lane = tid & 63, wave = tid >> 6;
  int wm = wave >> 1, wn = wave & 1;
  int l15 = lane & 15, quad = lane >> 4;
  int slot = (quad ^ ((l15 >> 1) & 3)) * 8;   // swizzled k-segment (shorts)
  int mrow = wm * 64 + l15;
  int nrow = wn * 32 + l15;

  stage(0, 0);
  for (int c = 0; c < 36; ++c) {
    __syncthreads();                       // drains stage(c); protects reuse
    if (c + 1 < 36) stage(c + 1, (c + 1) & 1);
    int q = c & 1;
    bf16x8 af[4], bfr[2];
#pragma unroll
    for (int mt = 0; mt < 4; ++mt)
      af[mt] = *(const bf16x8*)&Wlds[q][(mrow + mt * 16) * 32 + slot];
#pragma unroll
    for (int nt = 0; nt < 2; ++nt)
      bfr[nt] = *(const bf16x8*)&Plds[q][(nrow + nt * 16) * 32 + slot];
#pragma unroll
    for (int mt = 0; mt < 4; ++mt)
#pragma unroll
      for (int nt = 0; nt < 2; ++nt)
        acc[mt][nt] = __builtin_amdgcn_mfma_f32_16x16x32_bf16(
            af[mt], bfr[nt], acc[mt][nt], 0, 0, 0);
  }

  // epilogue: D col = lane&15 (pixel), row = quad*4 + r (co)
  // -> pixel-indexed outp[pix][co]; 512 B rows fully written, no partial lines
#pragma unroll
  for (int nt = 0; nt < 2; ++nt) {
    int n = wn * 32 + nt * 16 + l15;
    if ((nbase + n) >= cntp) continue;
    size_t rowb = (size_t)pixSB[n] * 256 + half * 128;
#pragma unroll
    for (int mt = 0; mt < 4; ++mt) {
      int co0 = wm * 64 + mt * 16 + quad * 4;
      float v0 = acc[mt][nt][0] + kbl[co0 + 0];
      float v1 = acc[mt][nt][1] + kbl[co0 + 1];
      float v2 = acc[mt][nt][2] + kbl[co0 + 2];
      float v3 = acc[mt][nt][3] + kbl[co0 + 3];
      v0 = v0 > 0.f ? v0 : 0.f;  v1 = v1 > 0.f ? v1 : 0.f;
      v2 = v2 > 0.f ? v2 : 0.f;  v3 = v3 > 0.f ? v3 : 0.f;
      u32 lo = (u32)f2bf(v0) | ((u32)f2bf(v1) << 16);
      u32 hi = (u32)f2bf(v2) | ((u32)f2bf(v3) << 16);
      *(u32*)&outp[rowb + co0]     = lo;
      *(u32*)&outp[rowb + co0 + 2] = hi;
    }
  }
}

// ---------------------------------------------------------------- streaming writer
__global__ __launch_bounds__(256) void k_out(
    const u32* __restrict__ outp, float* __restrict__ out) {
  __shared__ u32 t[64 * 129];              // +1 dword pad -> conflict-free
  int tid = threadIdx.x;
  int pix0 = blockIdx.x * 64;              // block stays in one b
  const u32* src = outp + (size_t)pix0 * 128;
  for (int i = tid; i < 8192; i += 256)    // contiguous 32 KB, coalesced
    t[(i >> 7) * 129 + (i & 127)] = src[i];
  __syncthreads();

  int ln = tid & 63, coq = tid >> 6;       // lanes = consecutive s
  int b = pix0 / 3136, s = pix0 - b * 3136 + ln;
  float* dst = out + (size_t)b * 802816 + s;
  const u32* row = &t[ln * 129 + coq * 32];
#pragma unroll
  for (int j = 0; j < 32; ++j) {
    u32 w = row[j];                        // 2-way bank alias (free)
    int co = 2 * (coq * 32 + j);
    dst[(size_t)co * 3136]       = bflo(w);
    dst[(size_t)(co + 1) * 3136] = bfhi(w);
  }
}

// ----------------------------------------------------------------
extern "C" void kernel_launch(void* const* d_in, const int* in_sizes, int n_in,
                              void* d_out, int out_size, void* d_ws, size_t ws_size,
                              hipStream_t stream) {
  const float* x   = (const float*)d_in[0];
  const float* kw  = (const float*)d_in[1];
  const float* kb  = (const float*)d_in[2];
  const float* ow1 = (const float*)d_in[3];
  const float* ob1 = (const float*)d_in[4];
  const float* ow2 = (const float*)d_in[5];
  const float* ob2 = (const float*)d_in[6];
  float* out = (float*)d_out;
  char* ws = (char*)d_ws;

  int* cnt  = (int*)(ws);
  int* list = (int*)(ws + OFF_LIST);
  u32* xpad = (u32*)(ws + OFF_XPAD);
  u32* w2   = (u32*)(ws + OFF_W2);
  unsigned short* outp = (unsigned short*)(ws + OFF_OUTP);

  hipMemsetAsync(cnt, 0, 64, stream);  // must precede k_front (obs atomics)

  k_front<<<1416, 512, 0, stream>>>(x, kw, ow1, ob1, ow2, ob2, xpad, w2,
                                    cnt, list);
  k_conv<<<802, 256, 0, stream>>>(cnt, list, (const char*)xpad, (const char*)w2,
                                  kb, outp);
  k_out<<<392, 256, 0, stream>>>((const u32*)outp, out);
}

// Round 10
// 157.172 us; speedup vs baseline: 1.2232x; 1.2232x over previous
//
#include <hip/hip_runtime.h>
#include <hip/hip_bf16.h>

// ProbableConv2d: selection-first implementation.
// B=8, CI=128, CO=256, H=W=56, P=9, K=3.
//
// 4 dispatches:
//   memset cnt (64 B)
//   k_front : fused, 512-thr blocks —
//             [0..391]    obs: fp32 observer -> argmax -> per-path lists.
//                         R10: whole 64px x 128ci x-slice (32 KB) staged to
//                         LDS ONCE via GLDS4 (wave w stages rows 16w..16w+15),
//                         ONE barrier, then 16 chunks of conflict-free
//                         ds_read_b32 + FMA. (R8: barrier/chunk = latency
//                         exposed 32x; R9: reg-prefetch = 84 VGPR, occupancy
//                         halved, 76us. Both structures beaten by stage-once.)
//             [392..839]  xpose: x -> x_pad NHWC bf16 via padded LDS tile.
//             [840..1415] wprep: kw -> W2 bf16 via LDS transpose, 4 pco/block.
//   k_conv  : per (path, co-half, 64-px tile) gathered-GEMM, MFMA bf16;
//             epilogue writes pixel-indexed outp[pix][co] bf16 (512 B rows
//             fully written -> no partial-line write amplification).
//   k_out   : pure streaming: contiguous outp reads -> LDS -> coalesced NCHW.

typedef unsigned int u32;

#define NPIX    25088      // 8*56*56
#define OFF_LIST 4096
#define OFF_XPAD 907264                      // 4096 + 9*25088*4
#define OFF_W2   7796736                     // + 8*58*58*128*2
#define OFF_OUTP 13105152                    // + 1327104*4  (outp: 25088*256*2 B)

__device__ __forceinline__ unsigned short f2bf(float f) {
  u32 u = __builtin_bit_cast(u32, f);
  u32 r = (u + 0x7FFFu + ((u >> 16) & 1u)) >> 16;
  return (unsigned short)r;
}
__device__ __forceinline__ float bflo(u32 w) {
  return __builtin_bit_cast(float, w << 16);
}
__device__ __forceinline__ float bfhi(u32 w) {
  return __builtin_bit_cast(float, w & 0xFFFF0000u);
}

#define GLDS16(g, l)                                                        \
  __builtin_amdgcn_global_load_lds(                                         \
      (const __attribute__((address_space(1))) u32*)(g),                    \
      (__attribute__((address_space(3))) u32*)(l), 16, 0, 0)
#define GLDS4(g, l)                                                         \
  __builtin_amdgcn_global_load_lds(                                         \
      (const __attribute__((address_space(1))) u32*)(g),                    \
      (__attribute__((address_space(3))) u32*)(l), 4, 0, 0)

typedef __attribute__((ext_vector_type(8))) short bf16x8;
typedef __attribute__((ext_vector_type(4))) float f32x4;

// ---------------------------------------------------------------- fused front-end
__global__ __launch_bounds__(512) void k_front(
    const float* __restrict__ x, const float* __restrict__ kw,
    const float* __restrict__ ow1, const float* __restrict__ ob1,
    const float* __restrict__ ow2, const float* __restrict__ ob2,
    u32* __restrict__ xpad, u32* __restrict__ w2,
    int* __restrict__ cnt, int* __restrict__ list) {
  // overlays: obs xs[128][64] f32 (32 KB) -> red[8][64][9] f32 (18.4 KB);
  //           xpose xt[56*65] u32 (14.6 KB); wprep kt[4608] f32 (18.4 KB)
  __shared__ __attribute__((aligned(16))) char smraw[32768];
  __shared__ int lcnt[9], lbase[9];

  int bid = blockIdx.x;
  int tid = threadIdx.x;
  int ln = tid & 63, wv = tid >> 6;

  if (bid < 392) {
    // ---------------- observer + argmax + compaction (64 px x 8 d-groups)
    float* xs  = (float*)smraw;          // [128][64] f32; [ci][px] -> 2-way free
    float* red = (float*)smraw;          // [8][64][9] overlay (after barrier)
    int dgu = __builtin_amdgcn_readfirstlane(wv);   // provably wave-uniform
    int pix0 = bid * 64;            // block stays in one b (3136 % 64 == 0)
    int b = pix0 / 3136, s0 = pix0 - b * 3136;
    int pix = pix0 + ln;
    const float* xsrc = x + (size_t)b * 401408 + s0 + ln;  // lane-consecutive

    // stage: wave wv loads rows 16*wv .. 16*wv+15 (256 B coalesced each)
#pragma unroll
    for (int r = 0; r < 16; ++r) {
      int row = dgu * 16 + r;                       // uniform per instr
      GLDS4(xsrc + (size_t)row * 3136, &xs[row * 64 + ln]);
    }

    if (tid < 9) lcnt[tid] = 0;

    float h[16];
    const float* o1 = ob1 + dgu * 16;               // scalar loads
#pragma unroll
    for (int i = 0; i < 16; ++i) h[i] = o1[i];
    const float* w1b = ow1 + dgu * 16 * 128;        // uniform base

    __syncthreads();                    // xs fully staged (vmcnt drained)

    for (int c = 0; c < 16; ++c) {      // pure LDS + FMA from here
      float xc[8];
#pragma unroll
      for (int j = 0; j < 8; ++j) xc[j] = xs[(c * 8 + j) * 64 + ln];
#pragma unroll
      for (int i = 0; i < 16; ++i) {
        const float* wr = w1b + i * 128 + c * 8;    // uniform -> s_load
        float a = h[i];
#pragma unroll
        for (int j = 0; j < 8; ++j) a = fmaf(wr[j], xc[j], a);
        h[i] = a;
      }
    }
    __syncthreads();                    // all xs reads done; red overlays

#pragma unroll
    for (int i = 0; i < 16; ++i) h[i] = tanhf(h[i]);

#pragma unroll
    for (int p = 0; p < 9; ++p) {
      float sc = 0.f;
      const float* wr = ow2 + p * 128 + dgu * 16;   // scalar loads
#pragma unroll
      for (int i = 0; i < 16; ++i) sc = fmaf(wr[i], h[i], sc);
      red[wv * 576 + ln * 9 + p] = sc;    // stride-9 -> 2-way alias (free)
    }
    __syncthreads();

    int bi = 0, slot = 0;
    if (wv == 0) {
      float best = 0.f;
#pragma unroll
      for (int p = 0; p < 9; ++p) {
        float v = ob2[p];
#pragma unroll
        for (int g = 0; g < 8; ++g) v += red[g * 576 + ln * 9 + p];  // asc-d
        if (p == 0 || v > best) { best = v; bi = p; }  // strict >: np argmax
      }
      slot = atomicAdd(&lcnt[bi], 1);     // LDS atomic
    }
    __syncthreads();
    if (tid < 9) lbase[tid] = atomicAdd(&cnt[tid], lcnt[tid]);
    __syncthreads();
    if (wv == 0) list[bi * NPIX + lbase[bi] + slot] = pix;

  } else if (bid < 840) {
    // ---------------- x (NCHW f32) -> x_pad row (b,h+1), fully coalesced
    u32* xt = (u32*)smraw;               // [56][65] padded
    int bh = bid - 392;                  // 0..447 = b*56+h
    int b = bh / 56, hh = bh - b * 56;
    const float* xr = x + (size_t)b * 401408 + hh * 56;
#pragma unroll
    for (int r = 0; r < 8; ++r) {
      int ci = wv * 16 + 2 * r;
      if (ln < 56) {
        float f0 = xr[(size_t)ci * 3136 + ln];
        float f1 = xr[(size_t)(ci + 1) * 3136 + ln];
        xt[ln * 65 + (ci >> 1)] = (u32)f2bf(f0) | ((u32)f2bf(f1) << 16);
      }
    }
    __syncthreads();
    u32* orow = xpad + (size_t)(b * 58 + hh + 1) * 58 * 64;
    for (int w = wv; w < 56; w += 8)
      orow[(w + 1) * 64 + ln] = xt[w * 65 + ln];
    if (wv == 0) orow[ln] = 0;                // halo col 0
    else if (wv == 1) orow[57 * 64 + ln] = 0; // halo col 57
    if (hh == 0) {
      u32* hrow = xpad + (size_t)(b * 58) * 58 * 64;
      for (int i = tid; i < 58 * 64; i += 512) hrow[i] = 0;
    } else if (hh == 55) {
      u32* hrow = xpad + (size_t)(b * 58 + 57) * 58 * 64;
      for (int i = tid; i < 58 * 64; i += 512) hrow[i] = 0;
    }

  } else {
    // ---------------- kw (P,CO,CI,3,3) f32 -> W2 (P,CO,1152) bf16, 4 pco/block
    float* kt = (float*)smraw;           // [4*1152]
    int base = (bid - 840) * 4;          // pco quad
    const float* src = kw + (size_t)base * 1152;
#pragma unroll
    for (int i = 0; i < 9; ++i) kt[i * 512 + tid] = src[i * 512 + tid];
    __syncthreads();
    for (int t = tid; t < 2304; t += 512) {
      int pl = t / 576, d = t - pl * 576;
      int tap = d >> 6, cp = d & 63;
      float v0 = kt[pl * 1152 + 18 * cp + tap];
      float v1 = kt[pl * 1152 + 18 * cp + 9 + tap];
      w2[(size_t)(base + pl) * 576 + d] = (u32)f2bf(v0) | ((u32)f2bf(v1) << 16);
    }
  }
}

// ---------------------------------------------------------------- gathered GEMM conv
__global__ __launch_bounds__(256, 4) void k_conv(
    const int* __restrict__ cnt, const int* __restrict__ list,
    const char* __restrict__ xpadB, const char* __restrict__ w2B,
    const float* __restrict__ kb, unsigned short* __restrict__ outp) {
  __shared__ short Wlds[2][4096];  // [buf][co(128) x k(32)], k-seg XOR-swizzled
  __shared__ short Plds[2][2048];  // [buf][px(64) x k(32)],  k-seg XOR-swizzled
  __shared__ int offsB[64], pixSB[64];
  __shared__ float kbl[128];

  int bid = blockIdx.x;
  int half = bid & 1, tb = bid >> 1;
  int p = -1, cntp = 0;
  for (int pp = 0; pp < 9; ++pp) {     // uniform scan: block -> (path, tile)
    int c = cnt[pp];
    int tt = (c + 63) >> 6;
    if (p < 0) {
      if (tb < tt) { p = pp; cntp = c; }
      else tb -= tt;
    }
  }
  if (p < 0) return;
  int nbase = tb * 64;
  int tid = threadIdx.x;

  if (tid < 64) {
    int g = nbase + tid;
    int pixid = list[p * NPIX + (g < cntp ? g : nbase)];
    int b = pixid / 3136, s = pixid - b * 3136;
    int h = s / 56, w = s - h * 56;
    offsB[tid] = ((b * 58 + h) * 58 + w) * 256;  // byte offset of tap(0,0)
    pixSB[tid] = pixid;
  }
  if (tid < 128) kbl[tid] = kb[p * 256 + half * 128 + tid];
  __syncthreads();

  // stage: LDS slot s of row r holds global k-segment s ^ ((r>>1)&3)
  int segsw = ((tid & 3) ^ ((tid >> 3) & 3)) * 16;   // byte offset of segment
  int na = tid >> 2;                                 // row 0..63
  int offP = offsB[na] + segsw;
  const char* wrow = w2B + (size_t)(p * 256 + half * 128) * 2304;
  const char* wp0 = wrow + (size_t)na * 2304 + segsw;
  const char* wp1 = wrow + (size_t)(64 + na) * 2304 + segsw;

  auto stage = [&](int c, int q) {
    int tap = c >> 2, kc = c & 3;
    int wko = tap * 256 + kc * 64;                          // bytes in W row
    int tapoff = ((tap / 3) * 58 + (tap % 3)) * 256 + kc * 64;  // bytes in x_pad
    GLDS16(wp0 + wko, &Wlds[q][tid * 8]);
    GLDS16(wp1 + wko, &Wlds[q][2048 + tid * 8]);
    GLDS16(xpadB + (size_t)(offP + tapoff), &Plds[q][tid * 8]);
  };

  f32x4 acc[4][2];
#pragma unroll
  for (int mt = 0; mt < 4; ++mt)
#pragma unroll
    for (int nt = 0; nt < 2; ++nt) acc[mt][nt] = (f32x4)0.f;

  int lane = tid & 63, wave = tid >> 6;
  int wm = wave >> 1, wn = wave & 1;
  int l15 = lane & 15, quad = lane >> 4;
  int slot = (quad ^ ((l15 >> 1) & 3)) * 8;   // swizzled k-segment (shorts)
  int mrow = wm * 64 + l15;
  int nrow = wn * 32 + l15;

  stage(0, 0);
  for (int c = 0; c < 36; ++c) {
    __syncthreads();                       // drains stage(c); protects reuse
    if (c + 1 < 36) stage(c + 1, (c + 1) & 1);
    int q = c & 1;
    bf16x8 af[4], bfr[2];
#pragma unroll
    for (int mt = 0; mt < 4; ++mt)
      af[mt] = *(const bf16x8*)&Wlds[q][(mrow + mt * 16) * 32 + slot];
#pragma unroll
    for (int nt = 0; nt < 2; ++nt)
      bfr[nt] = *(const bf16x8*)&Plds[q][(nrow + nt * 16) * 32 + slot];
#pragma unroll
    for (int mt = 0; mt < 4; ++mt)
#pragma unroll
      for (int nt = 0; nt < 2; ++nt)
        acc[mt][nt] = __builtin_amdgcn_mfma_f32_16x16x32_bf16(
            af[mt], bfr[nt], acc[mt][nt], 0, 0, 0);
  }

  // epilogue: D col = lane&15 (pixel), row = quad*4 + r (co)
  // -> pixel-indexed outp[pix][co]; 512 B rows fully written, no partial lines
#pragma unroll
  for (int nt = 0; nt < 2; ++nt) {
    int n = wn * 32 + nt * 16 + l15;
    if ((nbase + n) >= cntp) continue;
    size_t rowb = (size_t)pixSB[n] * 256 + half * 128;
#pragma unroll
    for (int mt = 0; mt < 4; ++mt) {
      int co0 = wm * 64 + mt * 16 + quad * 4;
      float v0 = acc[mt][nt][0] + kbl[co0 + 0];
      float v1 = acc[mt][nt][1] + kbl[co0 + 1];
      float v2 = acc[mt][nt][2] + kbl[co0 + 2];
      float v3 = acc[mt][nt][3] + kbl[co0 + 3];
      v0 = v0 > 0.f ? v0 : 0.f;  v1 = v1 > 0.f ? v1 : 0.f;
      v2 = v2 > 0.f ? v2 : 0.f;  v3 = v3 > 0.f ? v3 : 0.f;
      u32 lo = (u32)f2bf(v0) | ((u32)f2bf(v1) << 16);
      u32 hi = (u32)f2bf(v2) | ((u32)f2bf(v3) << 16);
      *(u32*)&outp[rowb + co0]     = lo;
      *(u32*)&outp[rowb + co0 + 2] = hi;
    }
  }
}

// ---------------------------------------------------------------- streaming writer
__global__ __launch_bounds__(256) void k_out(
    const u32* __restrict__ outp, float* __restrict__ out) {
  __shared__ u32 t[64 * 129];              // +1 dword pad -> conflict-free
  int tid = threadIdx.x;
  int pix0 = blockIdx.x * 64;              // block stays in one b
  const u32* src = outp + (size_t)pix0 * 128;
  for (int i = tid; i < 8192; i += 256)    // contiguous 32 KB, coalesced
    t[(i >> 7) * 129 + (i & 127)] = src[i];
  __syncthreads();

  int ln = tid & 63, coq = tid >> 6;       // lanes = consecutive s
  int b = pix0 / 3136, s = pix0 - b * 3136 + ln;
  float* dst = out + (size_t)b * 802816 + s;
  const u32* row = &t[ln * 129 + coq * 32];
#pragma unroll
  for (int j = 0; j < 32; ++j) {
    u32 w = row[j];                        // 2-way bank alias (free)
    int co = 2 * (coq * 32 + j);
    dst[(size_t)co * 3136]       = bflo(w);
    dst[(size_t)(co + 1) * 3136] = bfhi(w);
  }
}

// ----------------------------------------------------------------
extern "C" void kernel_launch(void* const* d_in, const int* in_sizes, int n_in,
                              void* d_out, int out_size, void* d_ws, size_t ws_size,
                              hipStream_t stream) {
  const float* x   = (const float*)d_in[0];
  const float* kw  = (const float*)d_in[1];
  const float* kb  = (const float*)d_in[2];
  const float* ow1 = (const float*)d_in[3];
  const float* ob1 = (const float*)d_in[4];
  const float* ow2 = (const float*)d_in[5];
  const float* ob2 = (const float*)d_in[6];
  float* out = (float*)d_out;
  char* ws = (char*)d_ws;

  int* cnt  = (int*)(ws);
  int* list = (int*)(ws + OFF_LIST);
  u32* xpad = (u32*)(ws + OFF_XPAD);
  u32* w2   = (u32*)(ws + OFF_W2);
  unsigned short* outp = (unsigned short*)(ws + OFF_OUTP);

  hipMemsetAsync(cnt, 0, 64, stream);  // must precede k_front (obs atomics)

  k_front<<<1416, 512, 0, stream>>>(x, kw, ow1, ob1, ow2, ob2, xpad, w2,
                                    cnt, list);
  k_conv<<<802, 256, 0, stream>>>(cnt, list, (const char*)xpad, (const char*)w2,
                                  kb, outp);
  k_out<<<392, 256, 0, stream>>>((const u32*)outp, out);
}